// Round 20
// baseline (138.404 us; speedup 1.0000x reference)
//
#include <hip/hip_runtime.h>
#include <math.h>

// ---- problem constants ----
#define NB      8
#define C_IN    3
#define HIMG    512
#define WIMG    512
#define C1      64      // conv1 out channels
#define HMID    256     // after pool1
#define WMID    256
#define C2      128     // conv2 out channels (C_FEAT)
#define HFT     128     // after pool2
#define WFT     128
#define NROIS   256
#define ROI_FT  32
#define SPP_DIM 2688    // 128*(1+4+16)
#define FC1_OUT 256
#define NCLS    1000

typedef unsigned short ushort;
typedef __attribute__((ext_vector_type(8))) short short8;
typedef __attribute__((ext_vector_type(4))) float f32x4;

#define GLOBAL_AS __attribute__((address_space(1)))
#define LDS_AS    __attribute__((address_space(3)))

static __device__ __forceinline__ ushort f2bf(float f) {
    unsigned u = __builtin_bit_cast(unsigned, f);
    unsigned r = (u + 0x7fffu + ((u >> 16) & 1u)) >> 16;   // RNE
    return (ushort)r;
}
static __device__ __forceinline__ float bf2f(ushort u) {
    return __builtin_bit_cast(float, (unsigned)u << 16);
}

// ---------------------------------------------------------------------------
// Kernel A+P: conv1 bf16 MFMA (z<8) fused with weight prep (z>=8).
// [byte-identical to R17/R19]
// ---------------------------------------------------------------------------
__global__ __launch_bounds__(512, 4)
void k_conv1_prep(const float* __restrict__ x, const float* __restrict__ w1,
                  const float* __restrict__ b1, ushort* __restrict__ mid,
                  const float* __restrict__ w2, const float* __restrict__ fc1w,
                  const float* __restrict__ fc2w, ushort* __restrict__ Wt2,
                  ushort* __restrict__ zp, ushort* __restrict__ f1T,
                  ushort* __restrict__ f2T)
{
    __shared__ ushort sm_x[3 * 34 * 68 + 8];     // 34 rows x stride 68 x 3 ci
    __shared__ float  sm_t[64][65];              // prep: transpose tile

    const int tid = threadIdx.x;

    if (blockIdx.z >= 8) {                       // ================ PREP ====
        int pid = (blockIdx.z - 8) * 128 + blockIdx.y * 8 + blockIdx.x;
        if (pid >= 376) return;
        if (pid < 144) {                         // ---- w2 -> Wt2 ----
            if (pid == 0 && tid < 64) zp[tid] = 0;
            int i = pid * 512 + tid;             // 73728 = 144*512
            int c   = i >> 12;
            int rem = i & 4095;
            int oc  = rem >> 5;
            int s   = rem & 31;
            int tap = c >> 1;
            int ci  = (c & 1) * 32 + s;
            Wt2[i] = f2bf(w2[(oc * 64 + ci) * 9 + tap]);
        } else if (pid < 312) {                  // ---- fc1_w transpose ----
            int j  = pid - 144;                  // 0..167 (42 x 4)
            int k0 = (j % 42) * 64;
            int n0 = (j / 42) * 64;
            #pragma unroll
            for (int s = 0; s < 8; ++s) {
                int idx = s * 512 + tid;
                int lk = idx >> 6, ln = idx & 63;
                sm_t[lk][ln] = fc1w[(size_t)(k0 + lk) * FC1_OUT + n0 + ln];
            }
            __syncthreads();
            #pragma unroll
            for (int s = 0; s < 8; ++s) {
                int idx = s * 512 + tid;
                int ln = idx >> 6, lk = idx & 63;
                f1T[(size_t)(n0 + ln) * SPP_DIM + k0 + lk] = f2bf(sm_t[lk][ln]);
            }
        } else {                                 // ---- fc2_w transpose ----
            int j  = pid - 312;                  // 0..63 (4 x 16)
            int k0 = (j & 3) * 64;
            int n0 = (j >> 2) * 64;
            #pragma unroll
            for (int s = 0; s < 8; ++s) {
                int idx = s * 512 + tid;
                int lk = idx >> 6, ln = idx & 63;
                sm_t[lk][ln] = (n0 + ln < NCLS) ? fc2w[(size_t)(k0 + lk) * NCLS + n0 + ln] : 0.f;
            }
            __syncthreads();
            #pragma unroll
            for (int s = 0; s < 8; ++s) {
                int idx = s * 512 + tid;
                int ln = idx >> 6, lk = idx & 63;
                f2T[(size_t)(n0 + ln) * FC1_OUT + k0 + lk] = f2bf(sm_t[lk][ln]);
            }
        }
        return;
    }

    // ================ CONV1 (64x x 32y tile, 8 subtiles of 4 conv rows) ====
    const int tx = blockIdx.x;    // 0..7  (64 conv cols)
    const int TY = blockIdx.y;    // 0..15 (32 conv rows)
    const int b  = blockIdx.z;

    const int cy0 = TY * 32, cx0 = tx * 64;

    // interior staging: aligned float4, 3ci x 34r x 16q = 1632 units
    for (int t = tid; t < 3 * 34 * 16; t += 512) {
        int ci  = t / 544;
        int rem = t - ci * 544;
        int r = rem >> 4, q = rem & 15;
        int gy = cy0 - 1 + r;
        ushort* dst = &sm_x[ci * 2312 + r * 68 + 1 + q * 4];
        if ((unsigned)gy < (unsigned)HIMG) {
            float4 v = *(const float4*)&x[((b * C_IN + ci) * HIMG + gy) * WIMG + cx0 + q * 4];
            dst[0] = f2bf(v.x); dst[1] = f2bf(v.y);
            dst[2] = f2bf(v.z); dst[3] = f2bf(v.w);
        } else {
            dst[0] = 0; dst[1] = 0; dst[2] = 0; dst[3] = 0;
        }
    }
    // halo columns: 3ci x 34r x 2 edges = 204 units
    if (tid < 204) {
        int ci  = tid / 68;
        int rem = tid - ci * 68;
        int r = rem >> 1, e = rem & 1;
        int gy = cy0 - 1 + r;
        int gx = e ? (cx0 + 64) : (cx0 - 1);
        int c  = e ? 65 : 0;
        float v = 0.f;
        if ((unsigned)gy < (unsigned)HIMG && (unsigned)gx < (unsigned)WIMG)
            v = x[((b * C_IN + ci) * HIMG + gy) * WIMG + gx];
        sm_x[ci * 2312 + r * 68 + c] = f2bf(v);
    }

    const int l   = tid & 63;
    const int wm  = tid >> 6;      // 0..7, conv-x offset wm*8
    const int c16 = l & 15;
    const int hi  = l >> 4;
    const int ylane = (c16 >> 1) & 1;
    const int xlane = ((c16 >> 2) << 1) | (c16 & 1);
    const int xloc  = wm * 8 + xlane;

    int offj[8];
    #pragma unroll
    for (int j = 0; j < 8; ++j) {
        int k = hi * 8 + j;
        int tap = k / 3, ci = k - 3 * tap;
        int dy = tap / 3, dx = tap - 3 * dy;
        offj[j] = (k < 27) ? (ci * 2312 + dy * 68 + dx) : 0;
    }

    // weight fragments straight from w1 (fp32, L2-hot): all 64 oc per wave
    short8 bf[4];
    float bb[4];
    #pragma unroll
    for (int fn = 0; fn < 4; ++fn) {
        int oc = fn * 16 + c16;
        union { ushort u[8]; short8 v; } wv;
        #pragma unroll
        for (int j = 0; j < 8; ++j) {
            int k = hi * 8 + j;
            float w = 0.f;
            if (k < 27) {
                int tap = k / 3, ci = k - 3 * tap;
                w = w1[oc * 27 + ci * 9 + tap];
            }
            wv.u[j] = f2bf(w);
        }
        bf[fn] = wv.v;
        bb[fn] = b1[oc];
    }
    __syncthreads();               // sm_x staged (overlaps weight gather)

    const int pxg = tx * 32 + wm * 4 + hi;     // pooled px global

    for (int s = 0; s < 8; ++s) {  // subtile: 4 conv rows -> 2 pooled rows
        f32x4 acc[2][4] = {};
        #pragma unroll
        for (int fm = 0; fm < 2; ++fm) {
            int base = (s * 4 + 2 * fm + ylane) * 68 + xloc;
            union { ushort u[8]; short8 v; } av;
            #pragma unroll
            for (int j = 0; j < 8; ++j) av.u[j] = sm_x[offj[j] + base];
            #pragma unroll
            for (int fn = 0; fn < 4; ++fn)
                acc[fm][fn] = __builtin_amdgcn_mfma_f32_16x16x32_bf16(
                    av.v, bf[fn], acc[fm][fn], 0, 0, 0);
        }

        // direct NHWC stores: lane completes lines across the fn loop
        #pragma unroll
        for (int fm = 0; fm < 2; ++fm) {
            int py = TY * 16 + s * 2 + fm;
            ushort* mp = mid + ((size_t)(b * HMID + py) * WMID + pxg) * C1;
            #pragma unroll
            for (int fn = 0; fn < 4; ++fn) {
                f32x4 a4 = acc[fm][fn];
                float m = fmaxf(fmaxf(a4[0], a4[1]), fmaxf(a4[2], a4[3]));
                mp[fn * 16 + c16] = f2bf(fmaxf(m + bb[fn], 0.f));
            }
        }
    }
}

// ---------------------------------------------------------------------------
// Kernel B: conv2 bf16 MFMA — R20: 2x2 wave split (wx = x-half, wn = oc-half)
// of the R19 4y x 32x / 256-thr / 26KB-LDS geometry. Per wave per chunk:
// 4 A ds_reads + 4 B loads + 16 MFMA. Block A-reads 32->16 (R19 binding pipe,
// 4x oc-redundant), B 8->16KB (still under MFMA issue). Reg count DROPS
// (A-state halves) -> 3 waves/SIMD preserved.
// ---------------------------------------------------------------------------
__global__ __launch_bounds__(256, 2)
void k_conv2_mfma(const ushort* __restrict__ mid, const ushort* __restrict__ Wt2,
                  const float* __restrict__ b2, const ushort* __restrict__ zp,
                  ushort* __restrict__ feat)
{
    __shared__ uint4 sm_in[1664];      // 26KB; slots 0..1631 = 204 pos x 8 gran

    const int tid = threadIdx.x;
    const int tx = blockIdx.x;         // 0..7   (32 conv cols each)
    const int ty = blockIdx.y;         // 0..63  (4 conv rows each)
    const int b  = blockIdx.z;

    const int cy0 = ty * 4, cx0 = tx * 32;

    // ---- stage halo tile: async global->LDS, source pre-swizzled ----
    #pragma unroll
    for (int i = 0; i < 7; ++i) {
        int t = i * 256 + tid;
        if (t < 1632) {
            int pos = t >> 3, g = t & 7;
            int hy  = pos / 34, hx = pos - hy * 34;
            int gy  = cy0 - 1 + hy, gx = cx0 - 1 + hx;
            bool ok = ((unsigned)gy < (unsigned)HMID) && ((unsigned)gx < (unsigned)WMID);
            const ushort* src = ok
                ? mid + (((size_t)(b * HMID + gy) * WMID + gx) * C1 + (g ^ (pos & 7)) * 8)
                : zp;
            __builtin_amdgcn_global_load_lds((const GLOBAL_AS void*)src,
                                             (LDS_AS void*)&sm_in[t], 16, 0, 0);
        }
    }
    __syncthreads();

    // ---- wave / lane decomposition: wx = x-half, wn = oc-half ----
    const int l   = tid & 63;
    const int wid = tid >> 6;       // 0..3
    const int wx  = wid & 1;        // x-offset wx*16
    const int wn  = wid >> 1;       // oc-offset wn*64
    const int c16 = l & 15;
    const int hi  = l >> 4;
    const int ylane = (c16 >> 1) & 1;
    const int xlane = ((c16 >> 2) << 1) | (c16 & 1);
    const int pos00 = ylane * 34 + wx * 16 + xlane;
    const ushort* wlane = Wt2 + (wn * 64 + c16) * 32 + hi * 8;

    f32x4 acc[2][2][4] = {};           // [xw][fm][fn]
    short8 acur[2][2], anxt[2][2], bcur[4], bnxt[4];

    #pragma unroll
    for (int xw = 0; xw < 2; ++xw)
        #pragma unroll
        for (int fm = 0; fm < 2; ++fm) {
            int pos = pos00 + xw * 8 + fm * 68;
            acur[xw][fm] = __builtin_bit_cast(short8, sm_in[pos * 8 + (hi ^ (pos & 7))]);
        }
    #pragma unroll
    for (int fn = 0; fn < 4; ++fn)
        bcur[fn] = *(const short8*)(wlane + fn * 512);

    #pragma unroll
    for (int c = 0; c < 18; ++c) {             // chunk: tap = c>>1, k0 = c&1
        const int cn   = (c < 17) ? c + 1 : 17;
        const int tapn = cn >> 1, k0n = cn & 1;
        const int dyn  = tapn / 3, dxn = tapn - 3 * dyn;
        #pragma unroll
        for (int xw = 0; xw < 2; ++xw)         // prefetch next A (LDS): 4 reads
            #pragma unroll
            for (int fm = 0; fm < 2; ++fm) {
                int pos = pos00 + xw * 8 + dyn * 34 + dxn + fm * 68;
                int gi  = (hi + k0n * 4) ^ (pos & 7);
                anxt[xw][fm] = __builtin_bit_cast(short8, sm_in[pos * 8 + gi]);
            }
        const ushort* wnp = wlane + cn * 4096;
        #pragma unroll
        for (int fn = 0; fn < 4; ++fn)         // prefetch next B: 4 loads (1KB dense)
            bnxt[fn] = *(const short8*)(wnp + fn * 512);

        __builtin_amdgcn_s_setprio(1);
        #pragma unroll
        for (int xw = 0; xw < 2; ++xw)
            #pragma unroll
            for (int fm = 0; fm < 2; ++fm)
                #pragma unroll
                for (int fn = 0; fn < 4; ++fn)
                    acc[xw][fm][fn] = __builtin_amdgcn_mfma_f32_16x16x32_bf16(
                        acur[xw][fm], bcur[fn], acc[xw][fm][fn], 0, 0, 0);
        __builtin_amdgcn_s_setprio(0);

        #pragma unroll
        for (int xw = 0; xw < 2; ++xw)
            #pragma unroll
            for (int fm = 0; fm < 2; ++fm) acur[xw][fm] = anxt[xw][fm];
        #pragma unroll
        for (int fn = 0; fn < 4; ++fn) bcur[fn] = bnxt[fn];
    }

    // ---- epilogue: pool 2x2 -> LDS [row2][px16][oc128] -> linear stores ----
    __syncthreads();                       // all waves done reading sm_in
    ushort* sm_o = (ushort*)sm_in;         // reuse: 2*16*128*2B = 8KB
    #pragma unroll
    for (int fn = 0; fn < 4; ++fn) {
        int oc = wn * 64 + fn * 16 + c16;
        float bb = b2[oc];
        #pragma unroll
        for (int xw = 0; xw < 2; ++xw) {
            int pxl = (wx * 2 + xw) * 4 + hi;  // 0..15
            #pragma unroll
            for (int fm = 0; fm < 2; ++fm) {
                f32x4 a4 = acc[xw][fm][fn];
                float m = fmaxf(fmaxf(a4[0], a4[1]), fmaxf(a4[2], a4[3]));
                sm_o[(fm * 16 + pxl) * 128 + oc] = f2bf(fmaxf(m + bb, 0.f));
            }
        }
    }
    __syncthreads();
    #pragma unroll
    for (int pass = 0; pass < 2; ++pass) { // 512 uint4s total (2 passes)
        int idx = pass * 256 + tid;        // 0..511
        int row = idx >> 8;                // 0..1 pooled row
        int off = idx & 255;               // 256 x 16B = 4KB per row
        uint4 v = *(const uint4*)(sm_o + (row * 16) * 128 + off * 8);
        int py = ty * 2 + row;
        uint4* dst = (uint4*)(feat + ((size_t)(b * HFT + py) * WFT + tx * 16) * C2) + off;
        *dst = v;
    }
}

// ---------------------------------------------------------------------------
// Kernel C: ROI crop + SPP. [byte-identical to R17/R19]
// ---------------------------------------------------------------------------
__global__ __launch_bounds__(512)
void k_roi_spp(const ushort* __restrict__ feat, const int* __restrict__ rois,
               ushort* __restrict__ spp)
{
    __shared__ float sm_blk[128 * 17];     // [ch][blk], pad 17

    const int tid = threadIdx.x;
    const int roi = blockIdx.x;

    const int bi = rois[roi * 5 + 0];
    int xm = (int)roundf((float)rois[roi * 5 + 1] * 0.25f);
    int ym = (int)roundf((float)rois[roi * 5 + 2] * 0.25f);
    xm = min(max(xm, 0), WFT - ROI_FT);
    ym = min(max(ym, 0), HFT - ROI_FT);

    const int cq  = tid & 31;              // ch-quad (4 ch each = 128 ch)
    const int blk = tid >> 5;              // 0..15 (by,bx) 8x8 block
    const int by  = blk >> 2, bx = blk & 3;
    const int ch0 = cq * 4;

    const ushort* base = feat
        + ((size_t)((bi * HFT + ym + by * 8)) * WFT + xm + bx * 8) * C2 + ch0;

    float mm[4];
    #pragma unroll
    for (int q = 0; q < 4; ++q) mm[q] = -INFINITY;

    #pragma unroll
    for (int y = 0; y < 8; ++y) {
        const ushort* rowp = base + (size_t)y * (WFT * C2);
        #pragma unroll
        for (int j = 0; j < 8; ++j) {
            uint2 v = *(const uint2*)(rowp + (size_t)j * C2);
            mm[0] = fmaxf(mm[0], __builtin_bit_cast(float, v.x << 16));
            mm[1] = fmaxf(mm[1], __builtin_bit_cast(float, v.x & 0xffff0000u));
            mm[2] = fmaxf(mm[2], __builtin_bit_cast(float, v.y << 16));
            mm[3] = fmaxf(mm[3], __builtin_bit_cast(float, v.y & 0xffff0000u));
        }
    }
    #pragma unroll
    for (int q = 0; q < 4; ++q)
        sm_blk[(ch0 + q) * 17 + blk] = mm[q];
    __syncthreads();

    if (tid < 128) {
        float v[16];
        #pragma unroll
        for (int k = 0; k < 16; ++k) v[k] = sm_blk[tid * 17 + k];
        ushort* o = spp + (size_t)roi * SPP_DIM;
        #pragma unroll
        for (int k = 0; k < 16; ++k) o[640 + tid * 16 + k] = f2bf(v[k]);
        float g = -INFINITY;
        #pragma unroll
        for (int qy = 0; qy < 2; ++qy) {
            #pragma unroll
            for (int qx = 0; qx < 2; ++qx) {
                float q = fmaxf(fmaxf(v[(2 * qy) * 4 + 2 * qx],     v[(2 * qy) * 4 + 2 * qx + 1]),
                                fmaxf(v[(2 * qy + 1) * 4 + 2 * qx], v[(2 * qy + 1) * 4 + 2 * qx + 1]));
                o[128 + tid * 4 + qy * 2 + qx] = f2bf(q);
                g = fmaxf(g, q);
            }
        }
        o[tid] = f2bf(g);
    }
}

// ---------------------------------------------------------------------------
// Kernel D: FC1 via bf16 MFMA, K-split x4 + N-split x2. [byte-identical R16]
// ---------------------------------------------------------------------------
__global__ __launch_bounds__(256)
void k_fc1(const ushort* __restrict__ spp, const ushort* __restrict__ f1T,
           const float* __restrict__ bias, ushort* __restrict__ h)
{
    __shared__ float sm_r[4 * 64 * 17];    // [wave][lane][16 vals], pad 17

    const int m0 = blockIdx.x * 32;     // 8 blocks
    const int n0 = blockIdx.y * 32;     // 8 blocks
    const int tid = threadIdx.x;
    const int wv  = tid >> 6;           // 0..3 — K-slice
    const int l   = tid & 63;
    const int c16 = l & 15, hi = l >> 4;

    const int kbase = wv * 672;         // 4 x 672 = 2688

    const ushort* ap0 = spp + (size_t)(m0 + c16) * SPP_DIM + kbase + hi * 8;
    const ushort* ap1 = ap0 + 16 * SPP_DIM;
    const ushort* bp[2];
    #pragma unroll
    for (int fn = 0; fn < 2; ++fn)
        bp[fn] = f1T + (size_t)(n0 + fn * 16 + c16) * SPP_DIM + kbase + hi * 8;

    f32x4 acc[2][2] = {};
    short8 a[2], bb[2], an[2], bn[2];
    a[0] = *(const short8*)(ap0);
    a[1] = *(const short8*)(ap1);
    bb[0] = *(const short8*)(bp[0]);
    bb[1] = *(const short8*)(bp[1]);

    for (int k0 = 0; k0 < 672; k0 += 32) {
        int kn = (k0 + 32 < 672) ? k0 + 32 : k0;
        an[0] = *(const short8*)(ap0 + kn);
        an[1] = *(const short8*)(ap1 + kn);
        bn[0] = *(const short8*)(bp[0] + kn);
        bn[1] = *(const short8*)(bp[1] + kn);
        #pragma unroll
        for (int fm = 0; fm < 2; ++fm)
            #pragma unroll
            for (int fn = 0; fn < 2; ++fn)
                acc[fm][fn] = __builtin_amdgcn_mfma_f32_16x16x32_bf16(
                    a[fm], bb[fn], acc[fm][fn], 0, 0, 0);
        a[0] = an[0]; a[1] = an[1];
        bb[0] = bn[0]; bb[1] = bn[1];
    }

    float* smw = sm_r + (wv * 64 + l) * 17;
    #pragma unroll
    for (int fm = 0; fm < 2; ++fm)
        #pragma unroll
        for (int fn = 0; fn < 2; ++fn) {
            f32x4 a4 = acc[fm][fn];
            #pragma unroll
            for (int r = 0; r < 4; ++r)
                smw[(fm * 2 + fn) * 4 + r] = a4[r];
        }
    __syncthreads();

    if (wv == 0) {
        #pragma unroll
        for (int fn = 0; fn < 2; ++fn) {
            int col = n0 + fn * 16 + c16;
            float bv = bias[col];
            #pragma unroll
            for (int fm = 0; fm < 2; ++fm) {
                #pragma unroll
                for (int r = 0; r < 4; ++r) {
                    int v = (fm * 2 + fn) * 4 + r;
                    float s = sm_r[l * 17 + v]
                            + sm_r[(64 + l) * 17 + v]
                            + sm_r[(128 + l) * 17 + v]
                            + sm_r[(192 + l) * 17 + v];
                    int row = m0 + fm * 16 + hi * 4 + r;
                    h[row * FC1_OUT + col] = f2bf(fmaxf(s + bv, 0.f));
                }
            }
        }
    }
}

// ---------------------------------------------------------------------------
// Kernel E: FC2 via bf16 MFMA + bias -> out f32 [256][1000]. [identical]
// ---------------------------------------------------------------------------
__global__ __launch_bounds__(64)
void k_fc2(const ushort* __restrict__ h, const ushort* __restrict__ f2T,
           const float* __restrict__ bias, float* __restrict__ out)
{
    const int m0 = blockIdx.x * 32;     // 8 blocks
    const int n0 = blockIdx.y * 64;     // 16 blocks (N padded to 1024)
    const int l  = threadIdx.x;
    const int c16 = l & 15, hi = l >> 4;

    f32x4 acc[2][4] = {};
    #pragma unroll
    for (int k0 = 0; k0 < FC1_OUT; k0 += 32) {
        short8 a[2], bb[4];
        #pragma unroll
        for (int fm = 0; fm < 2; ++fm)
            a[fm] = *(const short8*)(h + (size_t)(m0 + fm * 16 + c16) * FC1_OUT + k0 + hi * 8);
        #pragma unroll
        for (int fn = 0; fn < 4; ++fn)
            bb[fn] = *(const short8*)(f2T + (size_t)(n0 + fn * 16 + c16) * FC1_OUT + k0 + hi * 8);
        #pragma unroll
        for (int fm = 0; fm < 2; ++fm)
            #pragma unroll
            for (int fn = 0; fn < 4; ++fn)
                acc[fm][fn] = __builtin_amdgcn_mfma_f32_16x16x32_bf16(
                    a[fm], bb[fn], acc[fm][fn], 0, 0, 0);
    }
    #pragma unroll
    for (int fn = 0; fn < 4; ++fn) {
        int col = n0 + fn * 16 + c16;
        if (col < NCLS) {
            float bv = bias[col];
            #pragma unroll
            for (int fm = 0; fm < 2; ++fm) {
                f32x4 a4 = acc[fm][fn];
                #pragma unroll
                for (int r = 0; r < 4; ++r) {
                    int row = m0 + fm * 16 + hi * 4 + r;
                    out[row * NCLS + col] = a4[r] + bv;
                }
            }
        }
    }
}

// ---------------------------------------------------------------------------
extern "C" void kernel_launch(void* const* d_in, const int* in_sizes, int n_in,
                              void* d_out, int out_size, void* d_ws, size_t ws_size,
                              hipStream_t stream)
{
    const float* x     = (const float*)d_in[0];
    const int*   rois  = (const int*)  d_in[1];
    const float* w1    = (const float*)d_in[2];
    const float* b1    = (const float*)d_in[3];
    const float* w2    = (const float*)d_in[4];
    const float* b2    = (const float*)d_in[5];
    const float* fc1_w = (const float*)d_in[6];
    const float* fc1_b = (const float*)d_in[7];
    const float* fc2_w = (const float*)d_in[8];
    const float* fc2_b = (const float*)d_in[9];
    float* out = (float*)d_out;

    // workspace: mid | Wt2 | zp | feat | spp | h | f1T | f2T
    ushort* midb  = (ushort*)d_ws;
    ushort* Wt2   = midb  + (size_t)NB * HMID * WMID * C1;          // 33.55M
    ushort* zp    = Wt2   + 73728;                                  // 64
    ushort* featb = zp    + 64;
    ushort* sppb  = featb + (size_t)NB * HFT * WFT * C2;            // 16.78M
    ushort* hb    = sppb  + (size_t)NROIS * SPP_DIM;                // 688128
    ushort* f1T   = hb    + NROIS * FC1_OUT;                        // 65536
    ushort* f2T   = f1T   + (size_t)FC1_OUT * SPP_DIM;              // 688128

    k_conv1_prep<<<dim3(8, 16, 11), 512, 0, stream>>>(
        x, w1, b1, midb, w2, fc1_w, fc2_w, Wt2, zp, f1T, f2T);
    k_conv2_mfma<<<dim3(8, 64, NB), 256, 0, stream>>>(midb, Wt2, b2, zp, featb);
    k_roi_spp   <<<dim3(NROIS),     512, 0, stream>>>(featb, rois, sppb);
    k_fc1       <<<dim3(8, 8),      256, 0, stream>>>(sppb, f1T, fc1_b, hb);
    k_fc2       <<<dim3(8, 16),     64,  0, stream>>>(hb, f2T, fc2_b, out);
}

// Round 21
// 130.005 us; speedup vs baseline: 1.0646x; 1.0646x over previous
//
#include <hip/hip_runtime.h>
#include <math.h>

// ---- problem constants ----
#define NB      8
#define C_IN    3
#define HIMG    512
#define WIMG    512
#define C1      64      // conv1 out channels
#define HMID    256     // after pool1
#define WMID    256
#define C2      128     // conv2 out channels (C_FEAT)
#define HFT     128     // after pool2
#define WFT     128
#define NROIS   256
#define ROI_FT  32
#define SPP_DIM 2688    // 128*(1+4+16)
#define FC1_OUT 256
#define NCLS    1000

typedef unsigned short ushort;
typedef __attribute__((ext_vector_type(8))) short short8;
typedef __attribute__((ext_vector_type(4))) float f32x4;

#define GLOBAL_AS __attribute__((address_space(1)))
#define LDS_AS    __attribute__((address_space(3)))

static __device__ __forceinline__ ushort f2bf(float f) {
    unsigned u = __builtin_bit_cast(unsigned, f);
    unsigned r = (u + 0x7fffu + ((u >> 16) & 1u)) >> 16;   // RNE
    return (ushort)r;
}
static __device__ __forceinline__ float bf2f(ushort u) {
    return __builtin_bit_cast(float, (unsigned)u << 16);
}

// ---------------------------------------------------------------------------
// Kernel A+P: conv1 bf16 MFMA (z<8) fused with weight prep (z>=8).
// ---------------------------------------------------------------------------
__global__ __launch_bounds__(512, 4)
void k_conv1_prep(const float* __restrict__ x, const float* __restrict__ w1,
                  const float* __restrict__ b1, ushort* __restrict__ mid,
                  const float* __restrict__ w2, const float* __restrict__ fc1w,
                  const float* __restrict__ fc2w, ushort* __restrict__ Wt2,
                  ushort* __restrict__ zp, ushort* __restrict__ f1T,
                  ushort* __restrict__ f2T)
{
    __shared__ ushort sm_x[3 * 34 * 68 + 8];     // 34 rows x stride 68 x 3 ci
    __shared__ float  sm_t[64][65];              // prep: transpose tile

    const int tid = threadIdx.x;

    if (blockIdx.z >= 8) {                       // ================ PREP ====
        int pid = (blockIdx.z - 8) * 128 + blockIdx.y * 8 + blockIdx.x;
        if (pid >= 376) return;
        if (pid < 144) {                         // ---- w2 -> Wt2 ----
            if (pid == 0 && tid < 64) zp[tid] = 0;
            int i = pid * 512 + tid;             // 73728 = 144*512
            int c   = i >> 12;
            int rem = i & 4095;
            int oc  = rem >> 5;
            int s   = rem & 31;
            int tap = c >> 1;
            int ci  = (c & 1) * 32 + s;
            Wt2[i] = f2bf(w2[(oc * 64 + ci) * 9 + tap]);
        } else if (pid < 312) {                  // ---- fc1_w transpose ----
            int j  = pid - 144;                  // 0..167 (42 x 4)
            int k0 = (j % 42) * 64;
            int n0 = (j / 42) * 64;
            #pragma unroll
            for (int s = 0; s < 8; ++s) {
                int idx = s * 512 + tid;
                int lk = idx >> 6, ln = idx & 63;
                sm_t[lk][ln] = fc1w[(size_t)(k0 + lk) * FC1_OUT + n0 + ln];
            }
            __syncthreads();
            #pragma unroll
            for (int s = 0; s < 8; ++s) {
                int idx = s * 512 + tid;
                int ln = idx >> 6, lk = idx & 63;
                f1T[(size_t)(n0 + ln) * SPP_DIM + k0 + lk] = f2bf(sm_t[lk][ln]);
            }
        } else {                                 // ---- fc2_w transpose ----
            int j  = pid - 312;                  // 0..63 (4 x 16)
            int k0 = (j & 3) * 64;
            int n0 = (j >> 2) * 64;
            #pragma unroll
            for (int s = 0; s < 8; ++s) {
                int idx = s * 512 + tid;
                int lk = idx >> 6, ln = idx & 63;
                sm_t[lk][ln] = (n0 + ln < NCLS) ? fc2w[(size_t)(k0 + lk) * NCLS + n0 + ln] : 0.f;
            }
            __syncthreads();
            #pragma unroll
            for (int s = 0; s < 8; ++s) {
                int idx = s * 512 + tid;
                int ln = idx >> 6, lk = idx & 63;
                f2T[(size_t)(n0 + ln) * FC1_OUT + k0 + lk] = f2bf(sm_t[lk][ln]);
            }
        }
        return;
    }

    // ================ CONV1 (64x x 32y tile, 8 subtiles of 4 conv rows) ====
    const int tx = blockIdx.x;    // 0..7  (64 conv cols)
    const int TY = blockIdx.y;    // 0..15 (32 conv rows)
    const int b  = blockIdx.z;

    const int cy0 = TY * 32, cx0 = tx * 64;

    // interior staging: aligned float4, 3ci x 34r x 16q = 1632 units
    for (int t = tid; t < 3 * 34 * 16; t += 512) {
        int ci  = t / 544;
        int rem = t - ci * 544;
        int r = rem >> 4, q = rem & 15;
        int gy = cy0 - 1 + r;
        ushort* dst = &sm_x[ci * 2312 + r * 68 + 1 + q * 4];
        if ((unsigned)gy < (unsigned)HIMG) {
            float4 v = *(const float4*)&x[((b * C_IN + ci) * HIMG + gy) * WIMG + cx0 + q * 4];
            dst[0] = f2bf(v.x); dst[1] = f2bf(v.y);
            dst[2] = f2bf(v.z); dst[3] = f2bf(v.w);
        } else {
            dst[0] = 0; dst[1] = 0; dst[2] = 0; dst[3] = 0;
        }
    }
    // halo columns: 3ci x 34r x 2 edges = 204 units
    if (tid < 204) {
        int ci  = tid / 68;
        int rem = tid - ci * 68;
        int r = rem >> 1, e = rem & 1;
        int gy = cy0 - 1 + r;
        int gx = e ? (cx0 + 64) : (cx0 - 1);
        int c  = e ? 65 : 0;
        float v = 0.f;
        if ((unsigned)gy < (unsigned)HIMG && (unsigned)gx < (unsigned)WIMG)
            v = x[((b * C_IN + ci) * HIMG + gy) * WIMG + gx];
        sm_x[ci * 2312 + r * 68 + c] = f2bf(v);
    }

    const int l   = tid & 63;
    const int wm  = tid >> 6;      // 0..7, conv-x offset wm*8
    const int c16 = l & 15;
    const int hi  = l >> 4;
    const int ylane = (c16 >> 1) & 1;
    const int xlane = ((c16 >> 2) << 1) | (c16 & 1);
    const int xloc  = wm * 8 + xlane;

    int offj[8];
    #pragma unroll
    for (int j = 0; j < 8; ++j) {
        int k = hi * 8 + j;
        int tap = k / 3, ci = k - 3 * tap;
        int dy = tap / 3, dx = tap - 3 * dy;
        offj[j] = (k < 27) ? (ci * 2312 + dy * 68 + dx) : 0;
    }

    // weight fragments straight from w1 (fp32, L2-hot): all 64 oc per wave
    short8 bf[4];
    float bb[4];
    #pragma unroll
    for (int fn = 0; fn < 4; ++fn) {
        int oc = fn * 16 + c16;
        union { ushort u[8]; short8 v; } wv;
        #pragma unroll
        for (int j = 0; j < 8; ++j) {
            int k = hi * 8 + j;
            float w = 0.f;
            if (k < 27) {
                int tap = k / 3, ci = k - 3 * tap;
                w = w1[oc * 27 + ci * 9 + tap];
            }
            wv.u[j] = f2bf(w);
        }
        bf[fn] = wv.v;
        bb[fn] = b1[oc];
    }
    __syncthreads();               // sm_x staged (overlaps weight gather)

    const int pxg = tx * 32 + wm * 4 + hi;     // pooled px global

    for (int s = 0; s < 8; ++s) {  // subtile: 4 conv rows -> 2 pooled rows
        f32x4 acc[2][4] = {};
        #pragma unroll
        for (int fm = 0; fm < 2; ++fm) {
            int base = (s * 4 + 2 * fm + ylane) * 68 + xloc;
            union { ushort u[8]; short8 v; } av;
            #pragma unroll
            for (int j = 0; j < 8; ++j) av.u[j] = sm_x[offj[j] + base];
            #pragma unroll
            for (int fn = 0; fn < 4; ++fn)
                acc[fm][fn] = __builtin_amdgcn_mfma_f32_16x16x32_bf16(
                    av.v, bf[fn], acc[fm][fn], 0, 0, 0);
        }

        // direct NHWC stores: lane completes lines across the fn loop
        #pragma unroll
        for (int fm = 0; fm < 2; ++fm) {
            int py = TY * 16 + s * 2 + fm;
            ushort* mp = mid + ((size_t)(b * HMID + py) * WMID + pxg) * C1;
            #pragma unroll
            for (int fn = 0; fn < 4; ++fn) {
                f32x4 a4 = acc[fm][fn];
                float m = fmaxf(fmaxf(a4[0], a4[1]), fmaxf(a4[2], a4[3]));
                mp[fn * 16 + c16] = f2bf(fmaxf(m + bb[fn], 0.f));
            }
        }
    }
}

// ---------------------------------------------------------------------------
// Kernel B: conv2 bf16 MFMA — R19 OPTIMUM (reverted from R20's regression).
// 4y x 32x tile, 256 thr (4 oc-quarter waves), 26KB LDS, ~3 blocks/CU.
// Per wave per chunk: 8 A ds_reads + 2 B loads + 16 MFMA. B-L1 traffic is
// the binding resource (R10/R14/R20 evidence) — this config minimizes it.
// 69.4us, MfmaUtil 48%.
// ---------------------------------------------------------------------------
__global__ __launch_bounds__(256, 2)
void k_conv2_mfma(const ushort* __restrict__ mid, const ushort* __restrict__ Wt2,
                  const float* __restrict__ b2, const ushort* __restrict__ zp,
                  ushort* __restrict__ feat)
{
    __shared__ uint4 sm_in[1664];      // 26KB; slots 0..1631 = 204 pos x 8 gran

    const int tid = threadIdx.x;
    const int tx = blockIdx.x;         // 0..7   (32 conv cols each)
    const int ty = blockIdx.y;         // 0..63  (4 conv rows each)
    const int b  = blockIdx.z;

    const int cy0 = ty * 4, cx0 = tx * 32;

    // ---- stage halo tile: async global->LDS, source pre-swizzled ----
    #pragma unroll
    for (int i = 0; i < 7; ++i) {
        int t = i * 256 + tid;
        if (t < 1632) {
            int pos = t >> 3, g = t & 7;
            int hy  = pos / 34, hx = pos - hy * 34;
            int gy  = cy0 - 1 + hy, gx = cx0 - 1 + hx;
            bool ok = ((unsigned)gy < (unsigned)HMID) && ((unsigned)gx < (unsigned)WMID);
            const ushort* src = ok
                ? mid + (((size_t)(b * HMID + gy) * WMID + gx) * C1 + (g ^ (pos & 7)) * 8)
                : zp;
            __builtin_amdgcn_global_load_lds((const GLOBAL_AS void*)src,
                                             (LDS_AS void*)&sm_in[t], 16, 0, 0);
        }
    }
    __syncthreads();

    // ---- wave / lane decomposition: wave wn4 = oc quarter, covers all pos --
    const int l   = tid & 63;
    const int wn4 = tid >> 6;       // 0..3, oc-offset wn4*32
    const int c16 = l & 15;
    const int hi  = l >> 4;
    const int ylane = (c16 >> 1) & 1;
    const int xlane = ((c16 >> 2) << 1) | (c16 & 1);
    const int pos00 = ylane * 34 + xlane;
    const ushort* wlane = Wt2 + (wn4 * 32 + c16) * 32 + hi * 8;

    f32x4 acc[4][2][2] = {};           // [xw][fm][fn]
    short8 acur[4][2], anxt[4][2], bcur[2], bnxt[2];

    #pragma unroll
    for (int xw = 0; xw < 4; ++xw)
        #pragma unroll
        for (int fm = 0; fm < 2; ++fm) {
            int pos = pos00 + xw * 8 + fm * 68;
            acur[xw][fm] = __builtin_bit_cast(short8, sm_in[pos * 8 + (hi ^ (pos & 7))]);
        }
    #pragma unroll
    for (int fn = 0; fn < 2; ++fn)
        bcur[fn] = *(const short8*)(wlane + fn * 512);

    #pragma unroll
    for (int c = 0; c < 18; ++c) {             // chunk: tap = c>>1, k0 = c&1
        const int cn   = (c < 17) ? c + 1 : 17;
        const int tapn = cn >> 1, k0n = cn & 1;
        const int dyn  = tapn / 3, dxn = tapn - 3 * dyn;
        #pragma unroll
        for (int xw = 0; xw < 4; ++xw)         // prefetch next A (LDS): 8 reads
            #pragma unroll
            for (int fm = 0; fm < 2; ++fm) {
                int pos = pos00 + xw * 8 + dyn * 34 + dxn + fm * 68;
                int gi  = (hi + k0n * 4) ^ (pos & 7);
                anxt[xw][fm] = __builtin_bit_cast(short8, sm_in[pos * 8 + gi]);
            }
        const ushort* wnp = wlane + cn * 4096;
        #pragma unroll
        for (int fn = 0; fn < 2; ++fn)         // prefetch next B: 2 loads
            bnxt[fn] = *(const short8*)(wnp + fn * 512);

        __builtin_amdgcn_s_setprio(1);
        #pragma unroll
        for (int xw = 0; xw < 4; ++xw)
            #pragma unroll
            for (int fm = 0; fm < 2; ++fm)
                #pragma unroll
                for (int fn = 0; fn < 2; ++fn)
                    acc[xw][fm][fn] = __builtin_amdgcn_mfma_f32_16x16x32_bf16(
                        acur[xw][fm], bcur[fn], acc[xw][fm][fn], 0, 0, 0);
        __builtin_amdgcn_s_setprio(0);

        #pragma unroll
        for (int xw = 0; xw < 4; ++xw)
            #pragma unroll
            for (int fm = 0; fm < 2; ++fm) acur[xw][fm] = anxt[xw][fm];
        bcur[0] = bnxt[0]; bcur[1] = bnxt[1];
    }

    // ---- epilogue: pool 2x2 -> LDS [row2][px16][oc128] -> linear stores ----
    __syncthreads();                       // all waves done reading sm_in
    ushort* sm_o = (ushort*)sm_in;         // reuse: 2*16*128*2B = 8KB
    #pragma unroll
    for (int fn = 0; fn < 2; ++fn) {
        int oc = wn4 * 32 + fn * 16 + c16;
        float bb = b2[oc];
        #pragma unroll
        for (int xw = 0; xw < 4; ++xw) {
            int pxl = xw * 4 + hi;         // 0..15
            #pragma unroll
            for (int fm = 0; fm < 2; ++fm) {
                f32x4 a4 = acc[xw][fm][fn];
                float m = fmaxf(fmaxf(a4[0], a4[1]), fmaxf(a4[2], a4[3]));
                sm_o[(fm * 16 + pxl) * 128 + oc] = f2bf(fmaxf(m + bb, 0.f));
            }
        }
    }
    __syncthreads();
    #pragma unroll
    for (int pass = 0; pass < 2; ++pass) { // 512 uint4s total (2 passes)
        int idx = pass * 256 + tid;        // 0..511
        int row = idx >> 8;                // 0..1 pooled row
        int off = idx & 255;               // 256 x 16B = 4KB per row
        uint4 v = *(const uint4*)(sm_o + (row * 16) * 128 + off * 8);
        int py = ty * 2 + row;
        uint4* dst = (uint4*)(feat + ((size_t)(b * HFT + py) * WFT + tx * 16) * C2) + off;
        *dst = v;
    }
}

// ---------------------------------------------------------------------------
// Kernel C: ROI crop + SPP. [byte-identical to R17/R19]
// ---------------------------------------------------------------------------
__global__ __launch_bounds__(512)
void k_roi_spp(const ushort* __restrict__ feat, const int* __restrict__ rois,
               ushort* __restrict__ spp)
{
    __shared__ float sm_blk[128 * 17];     // [ch][blk], pad 17

    const int tid = threadIdx.x;
    const int roi = blockIdx.x;

    const int bi = rois[roi * 5 + 0];
    int xm = (int)roundf((float)rois[roi * 5 + 1] * 0.25f);
    int ym = (int)roundf((float)rois[roi * 5 + 2] * 0.25f);
    xm = min(max(xm, 0), WFT - ROI_FT);
    ym = min(max(ym, 0), HFT - ROI_FT);

    const int cq  = tid & 31;              // ch-quad (4 ch each = 128 ch)
    const int blk = tid >> 5;              // 0..15 (by,bx) 8x8 block
    const int by  = blk >> 2, bx = blk & 3;
    const int ch0 = cq * 4;

    const ushort* base = feat
        + ((size_t)((bi * HFT + ym + by * 8)) * WFT + xm + bx * 8) * C2 + ch0;

    float mm[4];
    #pragma unroll
    for (int q = 0; q < 4; ++q) mm[q] = -INFINITY;

    #pragma unroll
    for (int y = 0; y < 8; ++y) {
        const ushort* rowp = base + (size_t)y * (WFT * C2);
        #pragma unroll
        for (int j = 0; j < 8; ++j) {
            uint2 v = *(const uint2*)(rowp + (size_t)j * C2);
            mm[0] = fmaxf(mm[0], __builtin_bit_cast(float, v.x << 16));
            mm[1] = fmaxf(mm[1], __builtin_bit_cast(float, v.x & 0xffff0000u));
            mm[2] = fmaxf(mm[2], __builtin_bit_cast(float, v.y << 16));
            mm[3] = fmaxf(mm[3], __builtin_bit_cast(float, v.y & 0xffff0000u));
        }
    }
    #pragma unroll
    for (int q = 0; q < 4; ++q)
        sm_blk[(ch0 + q) * 17 + blk] = mm[q];
    __syncthreads();

    if (tid < 128) {
        float v[16];
        #pragma unroll
        for (int k = 0; k < 16; ++k) v[k] = sm_blk[tid * 17 + k];
        ushort* o = spp + (size_t)roi * SPP_DIM;
        #pragma unroll
        for (int k = 0; k < 16; ++k) o[640 + tid * 16 + k] = f2bf(v[k]);
        float g = -INFINITY;
        #pragma unroll
        for (int qy = 0; qy < 2; ++qy) {
            #pragma unroll
            for (int qx = 0; qx < 2; ++qx) {
                float q = fmaxf(fmaxf(v[(2 * qy) * 4 + 2 * qx],     v[(2 * qy) * 4 + 2 * qx + 1]),
                                fmaxf(v[(2 * qy + 1) * 4 + 2 * qx], v[(2 * qy + 1) * 4 + 2 * qx + 1]));
                o[128 + tid * 4 + qy * 2 + qx] = f2bf(q);
                g = fmaxf(g, q);
            }
        }
        o[tid] = f2bf(g);
    }
}

// ---------------------------------------------------------------------------
// Kernel D: FC1 via bf16 MFMA, K-split x4 + N-split x2. [byte-identical R16]
// ---------------------------------------------------------------------------
__global__ __launch_bounds__(256)
void k_fc1(const ushort* __restrict__ spp, const ushort* __restrict__ f1T,
           const float* __restrict__ bias, ushort* __restrict__ h)
{
    __shared__ float sm_r[4 * 64 * 17];    // [wave][lane][16 vals], pad 17

    const int m0 = blockIdx.x * 32;     // 8 blocks
    const int n0 = blockIdx.y * 32;     // 8 blocks
    const int tid = threadIdx.x;
    const int wv  = tid >> 6;           // 0..3 — K-slice
    const int l   = tid & 63;
    const int c16 = l & 15, hi = l >> 4;

    const int kbase = wv * 672;         // 4 x 672 = 2688

    const ushort* ap0 = spp + (size_t)(m0 + c16) * SPP_DIM + kbase + hi * 8;
    const ushort* ap1 = ap0 + 16 * SPP_DIM;
    const ushort* bp[2];
    #pragma unroll
    for (int fn = 0; fn < 2; ++fn)
        bp[fn] = f1T + (size_t)(n0 + fn * 16 + c16) * SPP_DIM + kbase + hi * 8;

    f32x4 acc[2][2] = {};
    short8 a[2], bb[2], an[2], bn[2];
    a[0] = *(const short8*)(ap0);
    a[1] = *(const short8*)(ap1);
    bb[0] = *(const short8*)(bp[0]);
    bb[1] = *(const short8*)(bp[1]);

    for (int k0 = 0; k0 < 672; k0 += 32) {
        int kn = (k0 + 32 < 672) ? k0 + 32 : k0;
        an[0] = *(const short8*)(ap0 + kn);
        an[1] = *(const short8*)(ap1 + kn);
        bn[0] = *(const short8*)(bp[0] + kn);
        bn[1] = *(const short8*)(bp[1] + kn);
        #pragma unroll
        for (int fm = 0; fm < 2; ++fm)
            #pragma unroll
            for (int fn = 0; fn < 2; ++fn)
                acc[fm][fn] = __builtin_amdgcn_mfma_f32_16x16x32_bf16(
                    a[fm], bb[fn], acc[fm][fn], 0, 0, 0);
        a[0] = an[0]; a[1] = an[1];
        bb[0] = bn[0]; bb[1] = bn[1];
    }

    float* smw = sm_r + (wv * 64 + l) * 17;
    #pragma unroll
    for (int fm = 0; fm < 2; ++fm)
        #pragma unroll
        for (int fn = 0; fn < 2; ++fn) {
            f32x4 a4 = acc[fm][fn];
            #pragma unroll
            for (int r = 0; r < 4; ++r)
                smw[(fm * 2 + fn) * 4 + r] = a4[r];
        }
    __syncthreads();

    if (wv == 0) {
        #pragma unroll
        for (int fn = 0; fn < 2; ++fn) {
            int col = n0 + fn * 16 + c16;
            float bv = bias[col];
            #pragma unroll
            for (int fm = 0; fm < 2; ++fm) {
                #pragma unroll
                for (int r = 0; r < 4; ++r) {
                    int v = (fm * 2 + fn) * 4 + r;
                    float s = sm_r[l * 17 + v]
                            + sm_r[(64 + l) * 17 + v]
                            + sm_r[(128 + l) * 17 + v]
                            + sm_r[(192 + l) * 17 + v];
                    int row = m0 + fm * 16 + hi * 4 + r;
                    h[row * FC1_OUT + col] = f2bf(fmaxf(s + bv, 0.f));
                }
            }
        }
    }
}

// ---------------------------------------------------------------------------
// Kernel E: FC2 via bf16 MFMA + bias -> out f32 [256][1000]. [identical]
// ---------------------------------------------------------------------------
__global__ __launch_bounds__(64)
void k_fc2(const ushort* __restrict__ h, const ushort* __restrict__ f2T,
           const float* __restrict__ bias, float* __restrict__ out)
{
    const int m0 = blockIdx.x * 32;     // 8 blocks
    const int n0 = blockIdx.y * 64;     // 16 blocks (N padded to 1024)
    const int l  = threadIdx.x;
    const int c16 = l & 15, hi = l >> 4;

    f32x4 acc[2][4] = {};
    #pragma unroll
    for (int k0 = 0; k0 < FC1_OUT; k0 += 32) {
        short8 a[2], bb[4];
        #pragma unroll
        for (int fm = 0; fm < 2; ++fm)
            a[fm] = *(const short8*)(h + (size_t)(m0 + fm * 16 + c16) * FC1_OUT + k0 + hi * 8);
        #pragma unroll
        for (int fn = 0; fn < 4; ++fn)
            bb[fn] = *(const short8*)(f2T + (size_t)(n0 + fn * 16 + c16) * FC1_OUT + k0 + hi * 8);
        #pragma unroll
        for (int fm = 0; fm < 2; ++fm)
            #pragma unroll
            for (int fn = 0; fn < 4; ++fn)
                acc[fm][fn] = __builtin_amdgcn_mfma_f32_16x16x32_bf16(
                    a[fm], bb[fn], acc[fm][fn], 0, 0, 0);
    }
    #pragma unroll
    for (int fn = 0; fn < 4; ++fn) {
        int col = n0 + fn * 16 + c16;
        if (col < NCLS) {
            float bv = bias[col];
            #pragma unroll
            for (int fm = 0; fm < 2; ++fm) {
                f32x4 a4 = acc[fm][fn];
                #pragma unroll
                for (int r = 0; r < 4; ++r) {
                    int row = m0 + fm * 16 + hi * 4 + r;
                    out[row * NCLS + col] = a4[r] + bv;
                }
            }
        }
    }
}

// ---------------------------------------------------------------------------
extern "C" void kernel_launch(void* const* d_in, const int* in_sizes, int n_in,
                              void* d_out, int out_size, void* d_ws, size_t ws_size,
                              hipStream_t stream)
{
    const float* x     = (const float*)d_in[0];
    const int*   rois  = (const int*)  d_in[1];
    const float* w1    = (const float*)d_in[2];
    const float* b1    = (const float*)d_in[3];
    const float* w2    = (const float*)d_in[4];
    const float* b2    = (const float*)d_in[5];
    const float* fc1_w = (const float*)d_in[6];
    const float* fc1_b = (const float*)d_in[7];
    const float* fc2_w = (const float*)d_in[8];
    const float* fc2_b = (const float*)d_in[9];
    float* out = (float*)d_out;

    // workspace: mid | Wt2 | zp | feat | spp | h | f1T | f2T
    ushort* midb  = (ushort*)d_ws;
    ushort* Wt2   = midb  + (size_t)NB * HMID * WMID * C1;          // 33.55M
    ushort* zp    = Wt2   + 73728;                                  // 64
    ushort* featb = zp    + 64;
    ushort* sppb  = featb + (size_t)NB * HFT * WFT * C2;            // 16.78M
    ushort* hb    = sppb  + (size_t)NROIS * SPP_DIM;                // 688128
    ushort* f1T   = hb    + NROIS * FC1_OUT;                        // 65536
    ushort* f2T   = f1T   + (size_t)FC1_OUT * SPP_DIM;              // 688128

    k_conv1_prep<<<dim3(8, 16, 11), 512, 0, stream>>>(
        x, w1, b1, midb, w2, fc1_w, fc2_w, Wt2, zp, f1T, f2T);
    k_conv2_mfma<<<dim3(8, 64, NB), 256, 0, stream>>>(midb, Wt2, b2, zp, featb);
    k_roi_spp   <<<dim3(NROIS),     512, 0, stream>>>(featb, rois, sppb);
    k_fc1       <<<dim3(8, 8),      256, 0, stream>>>(sppb, f1T, fc1_b, hb);
    k_fc2       <<<dim3(8, 16),     64,  0, stream>>>(hb, f2T, fc2_b, out);
}